// Round 8
// baseline (128.977 us; speedup 1.0000x reference)
//
#include <hip/hip_runtime.h>

// VectorQuantizer via fp8 MFMA + LDS-staged codebook (global_load_lds),
// fused last-block loss reduction.
// Prep stores E'' = -1024*e as fp8 e4m3, two K-halves interleaved per 16B
// slot, slots XOR-swizzled. acc = mfma_fp8(x8, E'', C=512) = 512*(1-2x.e) > 0
// (positive scale preserves packed-key order; ||e||^2 <= 6.1e-5 dropped —
// below key resolution). argmin via packed u32 keys: bits high 22 | code.
// Any argmin flip bounded elementwise by 2/1024 = 0.00195 << 0.025.
// out[0..N*D) = x + (q-x), out[N*D] = 1.25*mean((q-x)^2)  (exact fp32).

typedef __attribute__((ext_vector_type(4))) float f32x4;
typedef __attribute__((ext_vector_type(2))) unsigned long long u64x2;

constexpr int N_ROWS = 256 * 512;   // 131072
constexpr int D      = 64;
constexpr int K      = 1024;
constexpr int TPB    = 256;                      // 4 waves
constexpr int ROWS_PER_WAVE  = 16;
constexpr int ROWS_PER_BLOCK = 64;
constexpr int NBLK   = N_ROWS / ROWS_PER_BLOCK;  // 2048 -> 8 blocks/CU by grid
constexpr int CHUNK  = 128;                      // codes per LDS chunk (8 KB)
constexpr int NCHUNK = K / CHUNK;                // 8
constexpr int TPC    = CHUNK / 16;               // 8 MFMA tiles per chunk

// ---- prep: E -> fp8(-1024*e), K-halves interleaved, slot-swizzled ---------
// Layout: tile (16 codes) = 1 KB; code row = 64 B = 4 slots of 16 B.
// Logical slot s holds dims [8s,8s+8) then [32+8s,32+8s+8); physical slot
// index = s ^ ((crow>>1)&3)  (crow = code within tile).
__global__ __launch_bounds__(256) void vq_prep_kernel(
    const float* __restrict__ emb, uint4* __restrict__ ebf,
    unsigned* __restrict__ counter) {
  int k = blockIdx.x * 256 + threadIdx.x;
  if (k == 0) *counter = 0;           // reset fused-loss counter every call
  if (k >= K) return;
  const float* e = emb + (size_t)k * D;
  const int crow = k & 15;
  uint4* row = ebf + ((size_t)(k >> 4) * 1024 + (size_t)crow * 64) / 16;
  const int sw = (crow >> 1) & 3;
#pragma unroll
  for (int s = 0; s < 4; ++s) {
    float4 a0 = *(const float4*)(e + s * 8);
    float4 a1 = *(const float4*)(e + s * 8 + 4);
    float4 b0 = *(const float4*)(e + 32 + s * 8);
    float4 b1 = *(const float4*)(e + 32 + s * 8 + 4);
    const float sc = -1024.f;
    int d0 = 0, d1 = 0, d2 = 0, d3 = 0;
    d0 = __builtin_amdgcn_cvt_pk_fp8_f32(sc * a0.x, sc * a0.y, d0, false);
    d0 = __builtin_amdgcn_cvt_pk_fp8_f32(sc * a0.z, sc * a0.w, d0, true);
    d1 = __builtin_amdgcn_cvt_pk_fp8_f32(sc * a1.x, sc * a1.y, d1, false);
    d1 = __builtin_amdgcn_cvt_pk_fp8_f32(sc * a1.z, sc * a1.w, d1, true);
    d2 = __builtin_amdgcn_cvt_pk_fp8_f32(sc * b0.x, sc * b0.y, d2, false);
    d2 = __builtin_amdgcn_cvt_pk_fp8_f32(sc * b0.z, sc * b0.w, d2, true);
    d3 = __builtin_amdgcn_cvt_pk_fp8_f32(sc * b1.x, sc * b1.y, d3, false);
    d3 = __builtin_amdgcn_cvt_pk_fp8_f32(sc * b1.z, sc * b1.w, d3, true);
    uint4 slot;
    slot.x = (unsigned)d0; slot.y = (unsigned)d1;
    slot.z = (unsigned)d2; slot.w = (unsigned)d3;
    row[s ^ sw] = slot;
  }
}

// async 16B global -> LDS (linear dest: wave base + lane*16)
__device__ __forceinline__ void load16_lds(const uint4* g, void* l) {
  __builtin_amdgcn_global_load_lds(
      (const __attribute__((address_space(1))) unsigned*)g,
      (__attribute__((address_space(3))) unsigned*)l, 16, 0, 0);
}

// ---------------------------------------------------------------- main -----
__global__ __launch_bounds__(TPB, 6) void vq_main_kernel(
    const float* __restrict__ x, const uint4* __restrict__ ebf,
    const float* __restrict__ emb, float* __restrict__ out,
    float* __restrict__ partial, unsigned* __restrict__ counter) {
  __shared__ uint4 se[2][CHUNK * 4];      // 2 x 8 KB double buffer
  __shared__ int   s_bi[ROWS_PER_BLOCK]; // 256 B
  __shared__ float s_w[4];
  __shared__ bool  s_last;

  const int tid  = threadIdx.x;
  const int wave = tid >> 6, lane = tid & 63;
  const int lrow = lane & 15;   // A row / B col / C col
  const int kseg = lane >> 4;   // k-segment 0..3

  // Prologue: async-stage chunk 0 (2 x 1KB per wave, linear LDS).
#pragma unroll
  for (int i = 0; i < 2; ++i)
    load16_lds(ebf + wave * 128 + i * 64 + lane,
               (char*)&se[0][0] + wave * 2048 + i * 1024);

  const size_t rbase =
      (size_t)blockIdx.x * ROWS_PER_BLOCK + (size_t)wave * ROWS_PER_WAVE;

  // A fragment in fp8: lane holds row lrow; operand h covers
  // k = h*32 + kseg*8 .. +8 (8 bytes packed into an i64).
  long long xa[2];
  {
    const float* p = x + (rbase + lrow) * D + kseg * 8;
#pragma unroll
    for (int h = 0; h < 2; ++h) {
      float4 a = *(const float4*)(p + h * 32);
      float4 b = *(const float4*)(p + h * 32 + 4);
      int d0 = 0, d1 = 0;
      d0 = __builtin_amdgcn_cvt_pk_fp8_f32(a.x, a.y, d0, false);
      d0 = __builtin_amdgcn_cvt_pk_fp8_f32(a.z, a.w, d0, true);
      d1 = __builtin_amdgcn_cvt_pk_fp8_f32(b.x, b.y, d1, false);
      d1 = __builtin_amdgcn_cvt_pk_fp8_f32(b.z, b.w, d1, true);
      xa[h] = (long long)(((unsigned long long)(unsigned)d1 << 32) |
                          (unsigned long long)(unsigned)d0);
    }
  }

  unsigned kmin[4];
#pragma unroll
  for (int j = 0; j < 4; ++j) kmin[j] = 0xFFFFFFFFu;

  const f32x4 c512 = {512.f, 512.f, 512.f, 512.f};  // C-in: 512*(1-2x.e) > 0

  __syncthreads();  // chunk 0 landed (vmcnt drained by barrier)

  // Loop-invariant swizzled byte offset within a 16-code tile (1 KB):
  // one ds_read_b128 yields both K-half operands for this lane.
  const int off = lrow * 64 + ((kseg ^ ((lrow >> 1) & 3)) << 4);

  int cur = 0;
  for (int c = 0; c < NCHUNK; ++c) {
    // Async prefetch next chunk direct to LDS; lands before next barrier.
    if (c + 1 < NCHUNK) {
#pragma unroll
      for (int i = 0; i < 2; ++i)
        load16_lds(ebf + (c + 1) * 512 + wave * 128 + i * 64 + lane,
                   (char*)&se[cur ^ 1][0] + wave * 2048 + i * 1024);
    }

    const char* base = (const char*)&se[cur][0];
#pragma unroll
    for (int tt = 0; tt < TPC; ++tt) {
      u64x2 ev = *(const u64x2*)(base + (tt << 10) + off);
      const int kcode = c * CHUNK + tt * 16 + lrow;
      f32x4 acc = __builtin_amdgcn_mfma_f32_16x16x32_fp8_fp8(
          xa[0], (long long)ev[0], c512, 0, 0, 0);
      acc = __builtin_amdgcn_mfma_f32_16x16x32_fp8_fp8(
          xa[1], (long long)ev[1], acc, 0, 0, 0);
#pragma unroll
      for (int j = 0; j < 4; ++j) {   // acc[j] == 512*(dist+1) > 0
        unsigned key = (__builtin_bit_cast(unsigned, acc[j]) & 0xFFFFFC00u) |
                       (unsigned)kcode;
        kmin[j] = kmin[j] < key ? kmin[j] : key;
      }
    }
    __syncthreads();   // publish prefetched chunk; all reads of cur done
    cur ^= 1;
  }

  // Cross-col argmin over 16 lanes of each k-group; packed key min ==
  // (min dist, then min code) == jnp.argmin first-win semantics.
#pragma unroll
  for (int m = 1; m <= 8; m <<= 1) {
#pragma unroll
    for (int j = 0; j < 4; ++j) {
      unsigned o = (unsigned)__shfl_xor((int)kmin[j], m, 64);
      kmin[j] = kmin[j] < o ? kmin[j] : o;
    }
  }

  // C/D row = (lane>>4)*4 + j -> wave row kseg*4 + j.
  if (lrow < 4) {
    unsigned v = (lrow == 0) ? kmin[0] : (lrow == 1) ? kmin[1]
               : (lrow == 2) ? kmin[2] : kmin[3];
    s_bi[wave * ROWS_PER_WAVE + kseg * 4 + lrow] = (int)(v & 1023u);
  }
  __syncthreads();

  // Epilogue: 64 lanes cover 4 rows/group (1 KB contiguous per store).
  const int rig = lane >> 4;      // row in group
  const int chk = lane & 15;      // float4 chunk in row
  float lp = 0.f;
#pragma unroll
  for (int g = 0; g < ROWS_PER_WAVE / 4; ++g) {
    const int wrow = g * 4 + rig;
    const size_t r = rbase + wrow;
    const int bi = s_bi[wave * ROWS_PER_WAVE + wrow];
    float4 xv = ((const float4*)(x + r * D))[chk];
    float4 qv = ((const float4*)(emb + (size_t)bi * D))[chk];
    float dx = qv.x - xv.x, dy = qv.y - xv.y;
    float dz = qv.z - xv.z, dw = qv.w - xv.w;
    lp = fmaf(dx, dx, lp); lp = fmaf(dy, dy, lp);
    lp = fmaf(dz, dz, lp); lp = fmaf(dw, dw, lp);
    float4 ov;
    ov.x = xv.x + dx; ov.y = xv.y + dy;   // same rounding as x + sg(q-x)
    ov.z = xv.z + dz; ov.w = xv.w + dw;
    ((float4*)(out + r * D))[chk] = ov;
  }

#pragma unroll
  for (int o2 = 32; o2 > 0; o2 >>= 1) lp += __shfl_down(lp, o2, 64);
  if (lane == 0) s_w[wave] = lp;
  __syncthreads();

  // Fused loss: last block (device-scope counter) reduces all partials in a
  // fixed order -> deterministic. rocPRIM-style release/acquire fences.
  if (tid == 0) {
    partial[blockIdx.x] = (s_w[0] + s_w[1]) + (s_w[2] + s_w[3]);
    __threadfence();                       // release partial
    unsigned old = atomicAdd(counter, 1u); // device scope
    s_last = (old == (unsigned)(NBLK - 1));
  }
  __syncthreads();
  if (s_last) {
    __threadfence();                       // acquire all partials
    float v = 0.f;
#pragma unroll
    for (int i = 0; i < NBLK / TPB; ++i) v += partial[tid + i * TPB];
#pragma unroll
    for (int o2 = 32; o2 > 0; o2 >>= 1) v += __shfl_down(v, o2, 64);
    if (lane == 0) s_w[wave] = v;
    __syncthreads();
    if (tid == 0) {
      float total = (s_w[0] + s_w[1]) + (s_w[2] + s_w[3]);
      out[(size_t)N_ROWS * D] = 1.25f * total / (float)((size_t)N_ROWS * D);
    }
  }
}

// ------------------------------------------------------------- launch ------
extern "C" void kernel_launch(void* const* d_in, const int* in_sizes, int n_in,
                              void* d_out, int out_size, void* d_ws,
                              size_t ws_size, hipStream_t stream) {
  const float* x   = (const float*)d_in[0];   // [131072, 64] fp32
  const float* emb = (const float*)d_in[1];   // [1024, 64] fp32
  float* out = (float*)d_out;

  char* ws = (char*)d_ws;
  float*    partial = (float*)ws;                // 8 KB (NBLK floats)
  unsigned* counter = (unsigned*)(ws + 8192);    // 4 B
  uint4*    ebf     = (uint4*)(ws + 12288);      // 64 KB fp8 codebook

  vq_prep_kernel<<<K / 256, 256, 0, stream>>>(emb, ebf, counter);
  vq_main_kernel<<<NBLK, TPB, 0, stream>>>(x, ebf, emb, out, partial, counter);
}

// Round 9
// 40.255 us; speedup vs baseline: 3.2040x; 3.2040x over previous
//
#include <hip/hip_runtime.h>

// VectorQuantizer via fp8 MFMA + LDS-staged codebook + fence-free fused loss.
// Prep stores E'' = -1024*e as fp8 e4m3, two K-halves interleaved per 16B
// slot, slots XOR-swizzled. acc = mfma_fp8(x8, E'', C=512) = 512*(1-2x.e) > 0
// (positive scale preserves packed-key order; ||e||^2 <= 6.1e-5 dropped —
// below key resolution). argmin via packed u32 keys: bits high 22 | code.
// Any argmin flip bounded elementwise by 2/1024 = 0.00195 << 0.025.
// Loss fused via ONE u64 atomicAdd per block: {count<<52 | partial*2^16} —
// integer adds commute exactly (deterministic), value travels through the
// atomic cell so NO threadfence is needed (R8's fence storm: 129us).
// out[0..N*D) = x + (q-x), out[N*D] = 1.25*mean((q-x)^2).

typedef __attribute__((ext_vector_type(4))) float f32x4;
typedef __attribute__((ext_vector_type(2))) unsigned long long u64x2;

constexpr int N_ROWS = 256 * 512;   // 131072
constexpr int D      = 64;
constexpr int K      = 1024;
constexpr int TPB    = 256;                      // 4 waves
constexpr int ROWS_PER_WAVE  = 32;
constexpr int ROWS_PER_BLOCK = 128;
constexpr int NBLK   = N_ROWS / ROWS_PER_BLOCK;  // 1024 -> 4 blocks/CU
constexpr int CHUNK  = 256;                      // codes per LDS chunk (16 KB)
constexpr int NCHUNK = K / CHUNK;                // 4 barrier rounds
constexpr int TPC    = CHUNK / 16;               // 16 MFMA tiles per chunk

// ---- prep: E -> fp8(-1024*e), K-halves interleaved, slot-swizzled ---------
// Layout: tile (16 codes) = 1 KB; code row = 64 B = 4 slots of 16 B.
// Logical slot s holds dims [8s,8s+8) then [32+8s,32+8s+8); physical slot
// index = s ^ ((crow>>1)&3)  (crow = code within tile).
__global__ __launch_bounds__(256) void vq_prep_kernel(
    const float* __restrict__ emb, uint4* __restrict__ ebf,
    unsigned long long* __restrict__ acc64) {
  int k = blockIdx.x * 256 + threadIdx.x;
  if (k == 0) *acc64 = 0ULL;          // reset fused-loss accumulator per call
  if (k >= K) return;
  const float* e = emb + (size_t)k * D;
  const int crow = k & 15;
  uint4* row = ebf + ((size_t)(k >> 4) * 1024 + (size_t)crow * 64) / 16;
  const int sw = (crow >> 1) & 3;
#pragma unroll
  for (int s = 0; s < 4; ++s) {
    float4 a0 = *(const float4*)(e + s * 8);
    float4 a1 = *(const float4*)(e + s * 8 + 4);
    float4 b0 = *(const float4*)(e + 32 + s * 8);
    float4 b1 = *(const float4*)(e + 32 + s * 8 + 4);
    const float sc = -1024.f;
    int d0 = 0, d1 = 0, d2 = 0, d3 = 0;
    d0 = __builtin_amdgcn_cvt_pk_fp8_f32(sc * a0.x, sc * a0.y, d0, false);
    d0 = __builtin_amdgcn_cvt_pk_fp8_f32(sc * a0.z, sc * a0.w, d0, true);
    d1 = __builtin_amdgcn_cvt_pk_fp8_f32(sc * a1.x, sc * a1.y, d1, false);
    d1 = __builtin_amdgcn_cvt_pk_fp8_f32(sc * a1.z, sc * a1.w, d1, true);
    d2 = __builtin_amdgcn_cvt_pk_fp8_f32(sc * b0.x, sc * b0.y, d2, false);
    d2 = __builtin_amdgcn_cvt_pk_fp8_f32(sc * b0.z, sc * b0.w, d2, true);
    d3 = __builtin_amdgcn_cvt_pk_fp8_f32(sc * b1.x, sc * b1.y, d3, false);
    d3 = __builtin_amdgcn_cvt_pk_fp8_f32(sc * b1.z, sc * b1.w, d3, true);
    uint4 slot;
    slot.x = (unsigned)d0; slot.y = (unsigned)d1;
    slot.z = (unsigned)d2; slot.w = (unsigned)d3;
    row[s ^ sw] = slot;
  }
}

// ---------------------------------------------------------------- main -----
__global__ __launch_bounds__(TPB, 4) void vq_main_kernel(
    const float* __restrict__ x, const uint4* __restrict__ ebf,
    const float* __restrict__ emb, float* __restrict__ out,
    unsigned long long* __restrict__ acc64) {
  __shared__ uint4 se[2][CHUNK * 4];      // 2 x 16 KB double buffer
  __shared__ int   s_bi[ROWS_PER_BLOCK]; // 512 B
  __shared__ float s_w[TPB / 64];

  const int tid  = threadIdx.x;
  const int wave = tid >> 6, lane = tid & 63;
  const int lrow = lane & 15;   // A row / B col / C col
  const int kseg = lane >> 4;   // k-segment 0..3

  // Prologue staging (reg-staged, linear LDS writes): chunk 0.
  uint4 st0[4];
#pragma unroll
  for (int i = 0; i < 4; ++i) st0[i] = ebf[i * 256 + tid];

  const size_t rbase =
      (size_t)blockIdx.x * ROWS_PER_BLOCK + (size_t)wave * ROWS_PER_WAVE;

  // A fragments in fp8: lane holds row rg*16+lrow; operand h covers
  // k = h*32 + kseg*8 .. +8 (8 bytes packed into an i64).
  long long xa[2][2];
#pragma unroll
  for (int rg = 0; rg < 2; ++rg) {
    const float* p = x + (rbase + rg * 16 + lrow) * D + kseg * 8;
#pragma unroll
    for (int h = 0; h < 2; ++h) {
      float4 a = *(const float4*)(p + h * 32);
      float4 b = *(const float4*)(p + h * 32 + 4);
      int d0 = 0, d1 = 0;
      d0 = __builtin_amdgcn_cvt_pk_fp8_f32(a.x, a.y, d0, false);
      d0 = __builtin_amdgcn_cvt_pk_fp8_f32(a.z, a.w, d0, true);
      d1 = __builtin_amdgcn_cvt_pk_fp8_f32(b.x, b.y, d1, false);
      d1 = __builtin_amdgcn_cvt_pk_fp8_f32(b.z, b.w, d1, true);
      xa[rg][h] = (long long)(((unsigned long long)(unsigned)d1 << 32) |
                              (unsigned long long)(unsigned)d0);
    }
  }

#pragma unroll
  for (int i = 0; i < 4; ++i) se[0][i * 256 + tid] = st0[i];

  unsigned kmin[2][4];
#pragma unroll
  for (int rg = 0; rg < 2; ++rg)
#pragma unroll
    for (int j = 0; j < 4; ++j) kmin[rg][j] = 0xFFFFFFFFu;

  const f32x4 c512 = {512.f, 512.f, 512.f, 512.f};  // C-in: 512*(1-2x.e) > 0

  __syncthreads();  // chunk 0 visible

  // Loop-invariant swizzled byte offset within a 16-code tile (1 KB):
  // one ds_read_b128 yields both K-half operands for this lane.
  const int off = lrow * 64 + ((kseg ^ ((lrow >> 1) & 3)) << 4);

  int cur = 0;
  for (int c = 0; c < NCHUNK; ++c) {
    // T14 issue-early: next chunk's global loads before compute.
    uint4 stg[4];
    if (c + 1 < NCHUNK) {
#pragma unroll
      for (int i = 0; i < 4; ++i)
        stg[i] = ebf[(c + 1) * 1024 + i * 256 + tid];
    }

    const char* base = (const char*)&se[cur][0];
#pragma unroll
    for (int tt = 0; tt < TPC; ++tt) {
      u64x2 ev = *(const u64x2*)(base + (tt << 10) + off);
      const int kcode = c * CHUNK + tt * 16 + lrow;
#pragma unroll
      for (int rg = 0; rg < 2; ++rg) {
        f32x4 acc = __builtin_amdgcn_mfma_f32_16x16x32_fp8_fp8(
            xa[rg][0], (long long)ev[0], c512, 0, 0, 0);
        acc = __builtin_amdgcn_mfma_f32_16x16x32_fp8_fp8(
            xa[rg][1], (long long)ev[1], acc, 0, 0, 0);
#pragma unroll
        for (int j = 0; j < 4; ++j) {   // acc[j] == 512*(dist+1) > 0
          unsigned key = (__builtin_bit_cast(unsigned, acc[j]) & 0xFFFFFC00u) |
                         (unsigned)kcode;
          kmin[rg][j] = kmin[rg][j] < key ? kmin[rg][j] : key;
        }
      }
    }

    // T14 write-late: ds_write next chunk (linear, conflict-free), 1 barrier.
    if (c + 1 < NCHUNK) {
#pragma unroll
      for (int i = 0; i < 4; ++i) se[cur ^ 1][i * 256 + tid] = stg[i];
    }
    __syncthreads();
    cur ^= 1;
  }

  // Cross-col argmin over 16 lanes of each k-group; packed key min ==
  // (min dist, then min code) == jnp.argmin first-win semantics.
#pragma unroll
  for (int m = 1; m <= 8; m <<= 1) {
#pragma unroll
    for (int rg = 0; rg < 2; ++rg)
#pragma unroll
      for (int j = 0; j < 4; ++j) {
        unsigned o = (unsigned)__shfl_xor((int)kmin[rg][j], m, 64);
        kmin[rg][j] = kmin[rg][j] < o ? kmin[rg][j] : o;
      }
  }

  // C/D row = (lane>>4)*4 + j -> wave row rg*16 + kseg*4 + j.
  // s_bi is written and read by the SAME wave -> no __syncthreads needed
  // (per-wave LDS ordering via lgkmcnt); waves drain into the epilogue
  // independently.
  if (lrow < 4) {
#pragma unroll
    for (int rg = 0; rg < 2; ++rg) {
      unsigned v = (lrow == 0) ? kmin[rg][0] : (lrow == 1) ? kmin[rg][1]
                 : (lrow == 2) ? kmin[rg][2] : kmin[rg][3];
      s_bi[wave * ROWS_PER_WAVE + rg * 16 + kseg * 4 + lrow] =
          (int)(v & 1023u);
    }
  }

  // Epilogue: 64 lanes cover 4 rows/group (1 KB contiguous per store).
  const int rig = lane >> 4;      // row in group
  const int chk = lane & 15;      // float4 chunk in row
  float lp = 0.f;
#pragma unroll
  for (int g = 0; g < ROWS_PER_WAVE / 4; ++g) {
    const int wrow = g * 4 + rig;
    const size_t r = rbase + wrow;
    const int bi = s_bi[wave * ROWS_PER_WAVE + wrow];
    float4 xv = ((const float4*)(x + r * D))[chk];
    float4 qv = ((const float4*)(emb + (size_t)bi * D))[chk];
    float dx = qv.x - xv.x, dy = qv.y - xv.y;
    float dz = qv.z - xv.z, dw = qv.w - xv.w;
    lp = fmaf(dx, dx, lp); lp = fmaf(dy, dy, lp);
    lp = fmaf(dz, dz, lp); lp = fmaf(dw, dw, lp);
    float4 ov;
    ov.x = xv.x + dx; ov.y = xv.y + dy;   // same rounding as x + sg(q-x)
    ov.z = xv.z + dz; ov.w = xv.w + dw;
    ((float4*)(out + r * D))[chk] = ov;
  }

#pragma unroll
  for (int o2 = 32; o2 > 0; o2 >>= 1) lp += __shfl_down(lp, o2, 64);
  if (lane == 0) s_w[wave] = lp;
  __syncthreads();

  // Fence-free fused loss: one packed u64 atomicAdd per block.
  // bits [0,52): partial * 2^16 (block partial <= 2.7e5 -> sum < 2^44);
  // bits [52,63): block count. Integer adds are exactly commutative ->
  // deterministic. The block that completes the count owns the full sum
  // (old + pkt) with no visibility fence required.
  if (tid == 0) {
    float bp = (s_w[0] + s_w[1]) + (s_w[2] + s_w[3]);
    unsigned long long pkt =
        (unsigned long long)llrintf(bp * 65536.f) + (1ULL << 52);
    unsigned long long old = atomicAdd(acc64, pkt);
    if ((old >> 52) == (unsigned long long)(NBLK - 1)) {
      unsigned long long tot = (old + pkt) & ((1ULL << 52) - 1);
      out[(size_t)N_ROWS * D] =
          (float)(1.25 * ((double)tot / 65536.0) /
                  (double)((size_t)N_ROWS * D));
    }
  }
}

// ------------------------------------------------------------- launch ------
extern "C" void kernel_launch(void* const* d_in, const int* in_sizes, int n_in,
                              void* d_out, int out_size, void* d_ws,
                              size_t ws_size, hipStream_t stream) {
  const float* x   = (const float*)d_in[0];   // [131072, 64] fp32
  const float* emb = (const float*)d_in[1];   // [1024, 64] fp32
  float* out = (float*)d_out;

  char* ws = (char*)d_ws;
  unsigned long long* acc64 = (unsigned long long*)ws;   // 8 B
  uint4* ebf = (uint4*)(ws + 4096);                      // 64 KB fp8 codebook

  vq_prep_kernel<<<K / 256, 256, 0, stream>>>(emb, ebf, acc64);
  vq_main_kernel<<<NBLK, TPB, 0, stream>>>(x, ebf, emb, out, acc64);
}

// Round 10
// 34.461 us; speedup vs baseline: 3.7427x; 1.1681x over previous
//
#include <hip/hip_runtime.h>

// VectorQuantizer via fp8 MFMA + LDS-staged codebook.
// Prep stores E'' = -1024*e as fp8 e4m3, two K-halves interleaved per 16B
// slot, slots XOR-swizzled. acc = mfma_fp8(x8, E'', C=512) = 512*(1-2x.e) > 0
// (positive scale preserves packed-key order; ||e||^2 <= 6.1e-5 dropped —
// below key resolution). argmin via packed u32 keys: bits high 22 | code.
// Any argmin flip bounded elementwise by 2/1024 = 0.00195 << 0.025.
// RPW=16 / 2048 blocks: 6-8 blocks/CU for latency hiding (R8 showed 47%
// occupancy at this shape; its regression was the fence storm, now gone).
// out[0..N*D) = x + (q-x), out[N*D] = 1.25*mean((q-x)^2).

typedef __attribute__((ext_vector_type(4))) float f32x4;
typedef __attribute__((ext_vector_type(2))) unsigned long long u64x2;

constexpr int N_ROWS = 256 * 512;   // 131072
constexpr int D      = 64;
constexpr int K      = 1024;
constexpr int TPB    = 256;                      // 4 waves
constexpr int ROWS_PER_WAVE  = 16;
constexpr int ROWS_PER_BLOCK = 64;
constexpr int NBLK   = N_ROWS / ROWS_PER_BLOCK;  // 2048
constexpr int CHUNK  = 128;                      // codes per LDS chunk (8 KB)
constexpr int NCHUNK = K / CHUNK;                // 8
constexpr int TPC    = CHUNK / 16;               // 8 MFMA tiles per chunk

// ---- prep: E -> fp8(-1024*e), K-halves interleaved, slot-swizzled ---------
// Layout: tile (16 codes) = 1 KB; code row = 64 B = 4 slots of 16 B.
// Logical slot s holds dims [8s,8s+8) then [32+8s,32+8s+8); physical slot
// index = s ^ ((crow>>1)&3)  (crow = code within tile).
__global__ __launch_bounds__(64) void vq_prep_kernel(
    const float* __restrict__ emb, uint4* __restrict__ ebf) {
  int k = blockIdx.x * 64 + threadIdx.x;   // 16 blocks x 64 threads
  if (k >= K) return;
  const float* e = emb + (size_t)k * D;
  const int crow = k & 15;
  uint4* row = ebf + ((size_t)(k >> 4) * 1024 + (size_t)crow * 64) / 16;
  const int sw = (crow >> 1) & 3;
#pragma unroll
  for (int s = 0; s < 4; ++s) {
    float4 a0 = *(const float4*)(e + s * 8);
    float4 a1 = *(const float4*)(e + s * 8 + 4);
    float4 b0 = *(const float4*)(e + 32 + s * 8);
    float4 b1 = *(const float4*)(e + 32 + s * 8 + 4);
    const float sc = -1024.f;
    int d0 = 0, d1 = 0, d2 = 0, d3 = 0;
    d0 = __builtin_amdgcn_cvt_pk_fp8_f32(sc * a0.x, sc * a0.y, d0, false);
    d0 = __builtin_amdgcn_cvt_pk_fp8_f32(sc * a0.z, sc * a0.w, d0, true);
    d1 = __builtin_amdgcn_cvt_pk_fp8_f32(sc * a1.x, sc * a1.y, d1, false);
    d1 = __builtin_amdgcn_cvt_pk_fp8_f32(sc * a1.z, sc * a1.w, d1, true);
    d2 = __builtin_amdgcn_cvt_pk_fp8_f32(sc * b0.x, sc * b0.y, d2, false);
    d2 = __builtin_amdgcn_cvt_pk_fp8_f32(sc * b0.z, sc * b0.w, d2, true);
    d3 = __builtin_amdgcn_cvt_pk_fp8_f32(sc * b1.x, sc * b1.y, d3, false);
    d3 = __builtin_amdgcn_cvt_pk_fp8_f32(sc * b1.z, sc * b1.w, d3, true);
    uint4 slot;
    slot.x = (unsigned)d0; slot.y = (unsigned)d1;
    slot.z = (unsigned)d2; slot.w = (unsigned)d3;
    row[s ^ sw] = slot;
  }
}

// ---------------------------------------------------------------- main -----
__global__ __launch_bounds__(TPB, 6) void vq_main_kernel(
    const float* __restrict__ x, const uint4* __restrict__ ebf,
    const float* __restrict__ emb, float* __restrict__ out,
    float* __restrict__ partial) {
  __shared__ uint4 se[2][CHUNK * 4];      // 2 x 8 KB double buffer
  __shared__ int   s_bi[ROWS_PER_BLOCK]; // 256 B
  __shared__ float s_w[TPB / 64];

  const int tid  = threadIdx.x;
  const int wave = tid >> 6, lane = tid & 63;
  const int lrow = lane & 15;   // A row / B col / C col
  const int kseg = lane >> 4;   // k-segment 0..3

  // Prologue staging (reg-staged, linear LDS writes): chunk 0.
  uint4 st0[2];
#pragma unroll
  for (int i = 0; i < 2; ++i) st0[i] = ebf[i * 256 + tid];

  const size_t rbase =
      (size_t)blockIdx.x * ROWS_PER_BLOCK + (size_t)wave * ROWS_PER_WAVE;

  // A fragment in fp8: lane holds row lrow; operand h covers
  // k = h*32 + kseg*8 .. +8 (8 bytes packed into an i64).
  long long xa[2];
  {
    const float* p = x + (rbase + lrow) * D + kseg * 8;
#pragma unroll
    for (int h = 0; h < 2; ++h) {
      float4 a = *(const float4*)(p + h * 32);
      float4 b = *(const float4*)(p + h * 32 + 4);
      int d0 = 0, d1 = 0;
      d0 = __builtin_amdgcn_cvt_pk_fp8_f32(a.x, a.y, d0, false);
      d0 = __builtin_amdgcn_cvt_pk_fp8_f32(a.z, a.w, d0, true);
      d1 = __builtin_amdgcn_cvt_pk_fp8_f32(b.x, b.y, d1, false);
      d1 = __builtin_amdgcn_cvt_pk_fp8_f32(b.z, b.w, d1, true);
      xa[h] = (long long)(((unsigned long long)(unsigned)d1 << 32) |
                          (unsigned long long)(unsigned)d0);
    }
  }

#pragma unroll
  for (int i = 0; i < 2; ++i) se[0][i * 256 + tid] = st0[i];

  unsigned kmin[4];
#pragma unroll
  for (int j = 0; j < 4; ++j) kmin[j] = 0xFFFFFFFFu;

  const f32x4 c512 = {512.f, 512.f, 512.f, 512.f};  // C-in: 512*(1-2x.e) > 0

  __syncthreads();  // chunk 0 visible

  // Loop-invariant swizzled byte offset within a 16-code tile (1 KB):
  // one ds_read_b128 yields both K-half operands for this lane.
  const int off = lrow * 64 + ((kseg ^ ((lrow >> 1) & 3)) << 4);

  int cur = 0;
  for (int c = 0; c < NCHUNK; ++c) {
    // T14 issue-early: next chunk's global loads before compute.
    uint4 stg[2];
    if (c + 1 < NCHUNK) {
#pragma unroll
      for (int i = 0; i < 2; ++i)
        stg[i] = ebf[(c + 1) * 512 + i * 256 + tid];
    }

    const char* base = (const char*)&se[cur][0];
#pragma unroll
    for (int tt = 0; tt < TPC; ++tt) {
      u64x2 ev = *(const u64x2*)(base + (tt << 10) + off);
      const int kcode = c * CHUNK + tt * 16 + lrow;
      f32x4 acc = __builtin_amdgcn_mfma_f32_16x16x32_fp8_fp8(
          xa[0], (long long)ev[0], c512, 0, 0, 0);
      acc = __builtin_amdgcn_mfma_f32_16x16x32_fp8_fp8(
          xa[1], (long long)ev[1], acc, 0, 0, 0);
#pragma unroll
      for (int j = 0; j < 4; ++j) {   // acc[j] == 512*(dist+1) > 0
        unsigned key = (__builtin_bit_cast(unsigned, acc[j]) & 0xFFFFFC00u) |
                       (unsigned)kcode;
        kmin[j] = kmin[j] < key ? kmin[j] : key;
      }
    }

    // T14 write-late: ds_write next chunk (linear, conflict-free), 1 barrier.
    if (c + 1 < NCHUNK) {
#pragma unroll
      for (int i = 0; i < 2; ++i) se[cur ^ 1][i * 256 + tid] = stg[i];
    }
    __syncthreads();
    cur ^= 1;
  }

  // Cross-col argmin over 16 lanes of each k-group; packed key min ==
  // (min dist, then min code) == jnp.argmin first-win semantics.
#pragma unroll
  for (int m = 1; m <= 8; m <<= 1) {
#pragma unroll
    for (int j = 0; j < 4; ++j) {
      unsigned o = (unsigned)__shfl_xor((int)kmin[j], m, 64);
      kmin[j] = kmin[j] < o ? kmin[j] : o;
    }
  }

  // C/D row = (lane>>4)*4 + j -> wave row kseg*4 + j.
  // s_bi written and read by the SAME wave -> per-wave LDS ordering
  // suffices, no barrier; waves drain into the epilogue independently.
  if (lrow < 4) {
    unsigned v = (lrow == 0) ? kmin[0] : (lrow == 1) ? kmin[1]
               : (lrow == 2) ? kmin[2] : kmin[3];
    s_bi[wave * ROWS_PER_WAVE + kseg * 4 + lrow] = (int)(v & 1023u);
  }

  // Epilogue: 64 lanes cover 4 rows/group (1 KB contiguous per store).
  const int rig = lane >> 4;      // row in group
  const int chk = lane & 15;      // float4 chunk in row
  float lp = 0.f;
#pragma unroll
  for (int g = 0; g < ROWS_PER_WAVE / 4; ++g) {
    const int wrow = g * 4 + rig;
    const size_t r = rbase + wrow;
    const int bi = s_bi[wave * ROWS_PER_WAVE + wrow];
    float4 xv = ((const float4*)(x + r * D))[chk];
    float4 qv = ((const float4*)(emb + (size_t)bi * D))[chk];
    float dx = qv.x - xv.x, dy = qv.y - xv.y;
    float dz = qv.z - xv.z, dw = qv.w - xv.w;
    lp = fmaf(dx, dx, lp); lp = fmaf(dy, dy, lp);
    lp = fmaf(dz, dz, lp); lp = fmaf(dw, dw, lp);
    float4 ov;
    ov.x = xv.x + dx; ov.y = xv.y + dy;   // same rounding as x + sg(q-x)
    ov.z = xv.z + dz; ov.w = xv.w + dw;
    ((float4*)(out + r * D))[chk] = ov;
  }

#pragma unroll
  for (int o2 = 32; o2 > 0; o2 >>= 1) lp += __shfl_down(lp, o2, 64);
  if (lane == 0) s_w[wave] = lp;
  __syncthreads();
  if (tid == 0)
    partial[blockIdx.x] = (s_w[0] + s_w[1]) + (s_w[2] + s_w[3]);
}

// ---------------------------------------------------------------- loss -----
__global__ __launch_bounds__(256) void vq_loss_kernel(
    const float* __restrict__ partial, float* __restrict__ out) {
  __shared__ float wsum[4];
  int tid = threadIdx.x;
  float v = 0.f;
#pragma unroll
  for (int i = 0; i < NBLK / 256; ++i) v += partial[tid + i * 256];
#pragma unroll
  for (int off = 32; off > 0; off >>= 1) v += __shfl_down(v, off, 64);
  if ((tid & 63) == 0) wsum[tid >> 6] = v;
  __syncthreads();
  if (tid == 0) {
    float total = (wsum[0] + wsum[1]) + (wsum[2] + wsum[3]);
    out[(size_t)N_ROWS * D] = 1.25f * total / (float)((size_t)N_ROWS * D);
  }
}

// ------------------------------------------------------------- launch ------
extern "C" void kernel_launch(void* const* d_in, const int* in_sizes, int n_in,
                              void* d_out, int out_size, void* d_ws,
                              size_t ws_size, hipStream_t stream) {
  const float* x   = (const float*)d_in[0];   // [131072, 64] fp32
  const float* emb = (const float*)d_in[1];   // [1024, 64] fp32
  float* out = (float*)d_out;

  char* ws = (char*)d_ws;
  float* partial = (float*)ws;                 // 8 KB (NBLK floats)
  uint4* ebf     = (uint4*)(ws + 8192);        // 64 KB fp8 codebook

  vq_prep_kernel<<<16, 64, 0, stream>>>(emb, ebf);
  vq_main_kernel<<<NBLK, TPB, 0, stream>>>(x, ebf, emb, out, partial);
  vq_loss_kernel<<<1, 256, 0, stream>>>(partial, out);
}